// Round 1
// baseline (191.585 us; speedup 1.0000x reference)
//
#include <hip/hip_runtime.h>
#include <hip/hip_bf16.h>
#include <math.h>

#define B_ 8
#define N_ 4096
#define C_ 256
#define DQK_ 32

typedef float f32x4  __attribute__((ext_vector_type(4)));
typedef float f32x16 __attribute__((ext_vector_type(16)));
typedef short bf16x8 __attribute__((ext_vector_type(8)));
typedef short bf16x4 __attribute__((ext_vector_type(4)));

__device__ __forceinline__ short f2bf(float f){
  union { float f; unsigned u; } v; v.f = f;
  unsigned r = v.u + 0x7fffu + ((v.u >> 16) & 1u);
  return (short)(r >> 16);
}

// ---------- kernel 1: weight transpose + cast -> WT[320][256] bf16 ----------
__global__ void cast_wt_kernel(const float* __restrict__ Wq, const float* __restrict__ Wk,
                               const float* __restrict__ Wv, short* __restrict__ WT){
  int n = blockIdx.x;        // 0..319 output channel
  int k = threadIdx.x;       // 0..255 input channel
  float val;
  if (n < 32)       val = Wq[k*32 + n];
  else if (n < 64)  val = Wk[k*32 + (n-32)];
  else              val = Wv[k*256 + (n-64)];
  WT[n*256 + k] = f2bf(val);
}

// ---------- kernel 2: projections -> frag-swizzled q,k,v ----------
__global__ __launch_bounds__(256) void proj_kernel(
    const float* __restrict__ x, const short* __restrict__ WT,
    const float* __restrict__ bq, const float* __restrict__ bk, const float* __restrict__ bv,
    short* __restrict__ qws, short* __restrict__ kws, short* __restrict__ vSw){
  __shared__ __align__(16) short sX[64*264];   // 67584 B
  __shared__ __align__(16) short sT[64*72];    // 9216 B  (q cols 0..31 | k cols 32..63)
  int tid = threadIdx.x;
  int lane = tid & 63, wave = tid >> 6;
  int lane15 = lane & 15, quad = lane >> 4;
  int mbase = blockIdx.x * 64;
  int b = mbase >> 12, kvb = mbase & (N_-1);

  const float* xr = x + (size_t)mbase * C_;
  for (int i = 0; i < 8; i++){
    int s = tid + i*256;
    int row = s >> 5, cg = (s & 31) << 3;
    const f32x4* src = (const f32x4*)(xr + row*C_ + cg);
    f32x4 a = src[0], c = src[1];
    bf16x8 p;
    p[0]=f2bf(a[0]); p[1]=f2bf(a[1]); p[2]=f2bf(a[2]); p[3]=f2bf(a[3]);
    p[4]=f2bf(c[0]); p[5]=f2bf(c[1]); p[6]=f2bf(c[2]); p[7]=f2bf(c[3]);
    *(bf16x8*)(sX + row*264 + cg) = p;
  }
  __syncthreads();

  f32x4 acc[5][4];
  for (int i=0;i<5;i++) for (int mt=0;mt<4;mt++) acc[i][mt] = (f32x4)(0.f);

  for (int kc = 0; kc < 8; kc++){
    bf16x8 afr[4];
    #pragma unroll
    for (int mt=0;mt<4;mt++)
      afr[mt] = *(const bf16x8*)(sX + (mt*16+lane15)*264 + kc*32 + quad*8);
    bf16x8 bfr[5];
    #pragma unroll
    for (int i=0;i<5;i++){
      int t = i*4 + wave;
      bfr[i] = *(const bf16x8*)(WT + (size_t)(t*16+lane15)*256 + kc*32 + quad*8);
    }
    #pragma unroll
    for (int i=0;i<5;i++)
      #pragma unroll
      for (int mt=0;mt<4;mt++)
        acc[i][mt] = __builtin_amdgcn_mfma_f32_16x16x32_bf16(afr[mt], bfr[i], acc[i][mt], 0,0,0);
  }

  #pragma unroll
  for (int i=0;i<5;i++){
    int t = i*4 + wave;
    int n0 = t*16 + lane15;
    float bias = (n0 < 32) ? bq[n0] : (n0 < 64 ? bk[n0-32] : bv[n0-64]);
    if (n0 < 64){
      #pragma unroll
      for (int mt=0;mt<4;mt++)
        #pragma unroll
        for (int r=0;r<4;r++)
          sT[(mt*16 + quad*4 + r)*72 + n0] = f2bf(acc[i][mt][r] + bias);
    } else {
      int ch = n0 - 64, cht = ch >> 5, c5 = ch & 31;
      int lanep = c5 | ((quad & 1) << 5);
      int jo = (quad >> 1) * 4;
      #pragma unroll
      for (int mt=0;mt<4;mt++){
        bf16x4 pk;
        pk[0]=f2bf(acc[i][mt][0]+bias); pk[1]=f2bf(acc[i][mt][1]+bias);
        pk[2]=f2bf(acc[i][mt][2]+bias); pk[3]=f2bf(acc[i][mt][3]+bias);
        size_t off = (size_t)b*1048576 + (size_t)(kvb>>6)*16384
                   + (size_t)(mt*8 + cht)*512 + (size_t)lanep*8 + jo;
        *(bf16x4*)(vSw + off) = pk;
      }
    }
  }
  __syncthreads();

  {
    int qt = tid >> 7, p = (tid >> 6) & 1, ln = tid & 63;
    int row = qt*32 + (ln & 31);
    int dcol = p*16 + (ln >> 5)*8;
    bf16x8 vq = *(const bf16x8*)(sT + row*72 + dcol);
    bf16x8 vk = *(const bf16x8*)(sT + row*72 + 32 + dcol);
    size_t qoff = ((((size_t)b*128 + ((kvb>>5) + qt))*2 + p)*64 + ln)*8;
    *(bf16x8*)(qws + qoff) = vq;
    size_t koff = ((size_t)b*64 + (kvb>>6))*2048 + (size_t)((qt*2 + p)*64 + ln)*8;
    *(bf16x8*)(kws + koff) = vk;
  }
}

// ---------- kernel 3: flash attention + residual (v2: QK-ahead pipeline) ----------
// grid 256 (1 block/CU), block 512 thr = 8 waves (2/SIMD).
// wave w = qt*2+kh: q-tile qt (32 rows x 256 ch), kv-half kh of each 64-chunk.
// v2 changes vs v1:
//  * S(t+1) is computed DURING iteration t (QK-ahead); K-frags prefetched 2 chunks
//    ahead into ping-pong reg sets kA(even chunks)/kB(odd chunks). Loop is manually
//    2x-unrolled so every register index is compile-time static (no scratch).
//  * row-sum moved off the MFMA pipe: 2x mfma(pf,ones) -> 16 f32 VALU adds on the
//    exp values + one __shfl_xor(32) + 1KB LDS table at the end. MFMA work/iter
//    drops 20 -> 18.
__global__ __launch_bounds__(512, 2) void flash_kernel(
    const float* __restrict__ x, const short* __restrict__ qws, const short* __restrict__ kws,
    const short* __restrict__ vSw, const float* __restrict__ gptr, float* __restrict__ out){
  __shared__ __align__(16) char smem[66560];   // main: sV[2][32KB]; epilogue: 64KB R1 + 1KB TAB
  short* sV0 = (short*)smem;
  short* sV1 = (short*)(smem + 32768);
  int tid = threadIdx.x;
  int lane = tid & 63, wave = tid >> 6;
  int l31 = lane & 31, h = lane >> 5;
  int qt = wave >> 1, kh = wave & 1;
  int b = blockIdx.x & 7;
  int q0 = (blockIdx.x >> 3) << 7;

  const short* qb = qws + (size_t)b*131072;
  const short* kb = kws + (size_t)b*131072;
  const short* vb = vSw + (size_t)b*1048576;

  int qtg = (q0 >> 5) + qt;
  bf16x8 qf0 = *(const bf16x8*)(qb + (size_t)((qtg*2+0)*64 + lane)*8);
  bf16x8 qf1 = *(const bf16x8*)(qb + (size_t)((qtg*2+1)*64 + lane)*8);

  const short* kf0p = kb + (size_t)((2*kh+0)*64 + lane)*8;
  const short* kf1p = kb + (size_t)((2*kh+1)*64 + lane)*8;
  // K reg sets: kA holds even chunks, kB holds odd chunks (2-chunk prefetch depth)
  bf16x8 kA0 = *(const bf16x8*)(kf0p);
  bf16x8 kA1 = *(const bf16x8*)(kf1p);
  bf16x8 kB0 = *(const bf16x8*)(kf0p + 2048);
  bf16x8 kB1 = *(const bf16x8*)(kf1p + 2048);

#define VPREF(CHUNK, DST) do { \
    const short* vsrc_ = vb + (size_t)(CHUNK)*16384; \
    _Pragma("unroll") \
    for (int r_=0;r_<4;r_++) \
      __builtin_amdgcn_global_load_lds( \
        (const __attribute__((address_space(1))) void*)(vsrc_ + (size_t)(r_*512+tid)*8), \
        (__attribute__((address_space(3))) void*)((DST) + (size_t)(r_*512+tid)*8), 16, 0, 0); \
  } while(0)

#define QKS(K0, K1) ({ \
    f32x16 t_ = __builtin_amdgcn_mfma_f32_32x32x16_bf16((K0), qf0, (f32x16)(0.f), 0,0,0); \
    __builtin_amdgcn_mfma_f32_32x32x16_bf16((K1), qf1, t_, 0,0,0); })

#define EXPPACK(S, PF) do { \
    float ls_ = 0.f; \
    _Pragma("unroll") \
    for (int g_=0; g_<2; g_++){ \
      union { bf16x8 v; unsigned u[4]; } P_; \
      _Pragma("unroll") \
      for (int j_=0;j_<4;j_++){ \
        float2 e_; \
        e_.x = __expf((S)[g_*8 + 2*j_]); \
        e_.y = __expf((S)[g_*8 + 2*j_ + 1]); \
        ls_ += e_.x + e_.y; \
        __hip_bfloat162 t2_ = __float22bfloat162_rn(e_); \
        __builtin_memcpy(&P_.u[j_], &t2_, 4); \
      } \
      (PF)[g_] = P_.v; \
    } \
    rsum += ls_; \
  } while(0)

#define PV_STEP(SVC, PF) do { \
    _Pragma("unroll") \
    for (int g_=0; g_<2; g_++){ \
      const short* base_ = (SVC) + (2*kh + g_)*4096; \
      _Pragma("unroll") \
      for (int cht_=0; cht_<8; cht_++){ \
        bf16x8 vf_ = *(const bf16x8*)(base_ + (cht_*64 + lane)*8); \
        acc[cht_] = __builtin_amdgcn_mfma_f32_32x32x16_bf16((PF)[g_], vf_, acc[cht_], 0,0,0); \
      } \
    } \
  } while(0)

  VPREF(0, sV0);
  __syncthreads();

  f32x16 acc[8];
  #pragma unroll
  for (int t=0;t<8;t++) acc[t] = (f32x16)(0.f);
  float rsum = 0.f;

  // prologue: S(chunk0) from kA, then refill kA <- chunk2
  f32x16 s0 = QKS(kA0, kA1);
  f32x16 s1 = (f32x16)(0.f);
  kA0 = *(const bf16x8*)(kf0p + 2*2048);
  kA1 = *(const bf16x8*)(kf1p + 2*2048);

  for (int it2 = 0; it2 < 32; it2++){
    // ---- even chunk e = 2*it2 : consume s0, V in sV0 ----
    {
      VPREF(2*it2+1, sV1);                       // always valid (<= 63)
      bf16x8 pf[2];
      EXPPACK(s0, pf);
      s1 = QKS(kB0, kB1);                        // S(chunk 2*it2+1), K loaded 2 iters ago
      if (it2 < 31){                             // refill kB <- chunk 2*it2+3
        kB0 = *(const bf16x8*)(kf0p + (size_t)(2*it2+3)*2048);
        kB1 = *(const bf16x8*)(kf1p + (size_t)(2*it2+3)*2048);
      }
      PV_STEP(sV0, pf);
      __syncthreads();
    }
    // ---- odd chunk o = 2*it2+1 : consume s1, V in sV1 ----
    {
      if (it2 < 31) VPREF(2*it2+2, sV0);
      bf16x8 pf[2];
      EXPPACK(s1, pf);
      if (it2 < 31){
        s0 = QKS(kA0, kA1);                      // S(chunk 2*it2+2)
        if (it2 < 30){                           // refill kA <- chunk 2*it2+4
          kA0 = *(const bf16x8*)(kf0p + (size_t)(2*it2+4)*2048);
          kA1 = *(const bf16x8*)(kf1p + (size_t)(2*it2+4)*2048);
        }
      }
      PV_STEP(sV1, pf);
      __syncthreads();
    }
  }

  // ---- row-sum merge: h-pair via shfl, publish per-(wave,q) to 1KB LDS table ----
  float* R1 = (float*)smem;              // [wave][j(2)][i(16)][lane]  = 64 KB
  float* TAB = (float*)(smem + 65536);   // [wave][q(32)]              = 1 KB
  int pw = wave ^ 1;
  rsum += __shfl_xor(rsum, 32);          // merge h-interleaved kv rows (same q col)
  if (lane < 32) TAB[wave*32 + lane] = rsum;

  // ---- pair reduction over kv-halves (partner wave = wave^1), constant reg indices ----
  // phase 1: exchange first 2 accs of the half I'm NOT keeping
  if (kh == 0){
    #pragma unroll
    for (int i=0;i<16;i++){ R1[wave*2048 + i*64 + lane] = acc[4][i];
                            R1[wave*2048 + 1024 + i*64 + lane] = acc[5][i]; }
  } else {
    #pragma unroll
    for (int i=0;i<16;i++){ R1[wave*2048 + i*64 + lane] = acc[0][i];
                            R1[wave*2048 + 1024 + i*64 + lane] = acc[1][i]; }
  }
  __syncthreads();
  if (kh == 0){
    #pragma unroll
    for (int i=0;i<16;i++){ acc[0][i] += R1[pw*2048 + i*64 + lane];
                            acc[1][i] += R1[pw*2048 + 1024 + i*64 + lane]; }
  } else {
    #pragma unroll
    for (int i=0;i<16;i++){ acc[4][i] += R1[pw*2048 + i*64 + lane];
                            acc[5][i] += R1[pw*2048 + 1024 + i*64 + lane]; }
  }
  __syncthreads();
  // phase 2: exchange remaining 2 accs
  if (kh == 0){
    #pragma unroll
    for (int i=0;i<16;i++){ R1[wave*2048 + i*64 + lane] = acc[6][i];
                            R1[wave*2048 + 1024 + i*64 + lane] = acc[7][i]; }
  } else {
    #pragma unroll
    for (int i=0;i<16;i++){ R1[wave*2048 + i*64 + lane] = acc[2][i];
                            R1[wave*2048 + 1024 + i*64 + lane] = acc[3][i]; }
  }
  __syncthreads();
  if (kh == 0){
    #pragma unroll
    for (int i=0;i<16;i++){ acc[2][i] += R1[pw*2048 + i*64 + lane];
                            acc[3][i] += R1[pw*2048 + 1024 + i*64 + lane]; }
  } else {
    #pragma unroll
    for (int i=0;i<16;i++){ acc[6][i] += R1[pw*2048 + i*64 + lane];
                            acc[7][i] += R1[pw*2048 + 1024 + i*64 + lane]; }
  }

  // ---- epilogue: out = gamma*O/l + x ; wave owns rows [q0+32qt,+32) x ch [128kh,+128) ----
  float g = *gptr;
  const float* xb = x + ((size_t)b*N_ + q0 + qt*32)*C_;
  float*       ob = out + ((size_t)b*N_ + q0 + qt*32)*C_;
  if (kh == 0){
    #pragma unroll
    for (int i=0;i<16;i++){
      int q = (i&3) + 8*(i>>2) + 4*h;
      float rv = 1.f / (TAB[(qt*2+0)*32 + q] + TAB[(qt*2+1)*32 + q]);
      #pragma unroll
      for (int ct=0; ct<4; ct++){
        int ch = ct*32 + l31;
        ob[(size_t)q*C_ + ch] = g*(acc[ct][i]*rv) + xb[(size_t)q*C_ + ch];
      }
    }
  } else {
    #pragma unroll
    for (int i=0;i<16;i++){
      int q = (i&3) + 8*(i>>2) + 4*h;
      float rv = 1.f / (TAB[(qt*2+0)*32 + q] + TAB[(qt*2+1)*32 + q]);
      #pragma unroll
      for (int ct=0; ct<4; ct++){
        int ch = (4+ct)*32 + l31;
        ob[(size_t)q*C_ + ch] = g*(acc[4+ct][i]*rv) + xb[(size_t)q*C_ + ch];
      }
    }
  }
#undef VPREF
#undef QKS
#undef EXPPACK
#undef PV_STEP
}

extern "C" void kernel_launch(void* const* d_in, const int* in_sizes, int n_in,
                              void* d_out, int out_size, void* d_ws, size_t ws_size,
                              hipStream_t stream){
  const float* x  = (const float*)d_in[0];
  const float* Wq = (const float*)d_in[1];
  const float* bq = (const float*)d_in[2];
  const float* Wk = (const float*)d_in[3];
  const float* bk = (const float*)d_in[4];
  const float* Wv = (const float*)d_in[5];
  const float* bv = (const float*)d_in[6];
  const float* gm = (const float*)d_in[7];
  float* out = (float*)d_out;
  char* ws = (char*)d_ws;
  short* WT  = (short*)ws;                               // 163840 B
  short* qws = (short*)(ws + 163840);                    // 2097152 B
  short* kws = (short*)(ws + 163840 + 2097152);          // 2097152 B
  short* vSw = (short*)(ws + 163840 + 2*2097152);        // 16777216 B

  cast_wt_kernel<<<dim3(320), dim3(256), 0, stream>>>(Wq, Wk, Wv, WT);
  proj_kernel<<<dim3(512), dim3(256), 0, stream>>>(x, WT, bq, bk, bv, qws, kws, vSw);
  flash_kernel<<<dim3(256), dim3(512), 0, stream>>>(x, qws, kws, vSw, gm, out);
}